// Round 10
// baseline (76.235 us; speedup 1.0000x reference)
//
#include <hip/hip_runtime.h>
#include <hip/hip_bf16.h>

// score = sigmoid(relu([h[src]|h[dst]]@W1 + b1) @ W2 + b2)
// R10: R9 chain; single change = K1 occupancy fix.
//   K0: W1 -> bf16 fragment-ordered table (64 KB) in d_ws (after uv).
//   K1: node GEMM, no LDS/barriers; __launch_bounds__(256,3) (was (256,1):
//       1 blk/CU = 1 wave/SIMD = zero latency hiding -> ~15us; now 12
//       waves/CU, live set ~115 VGPR well under the 170 cap -> no spill).
//   K2: per-edge tail, UNCHANGED from R8/R9 (42 us, occ 68%, VGPR 24) --
//       suspected at the random-gather beyond-L2 wall (~3.7 TB/s delivered).

#define HID    128
#define NNODE  50000
#define NEDGE  600000
#define NGRP   ((NNODE + 31) / 32)       // 1563 node groups of 32
#define K1BLK  ((NGRP + 1) / 2)          // 782 blocks, 2 groups (4 waves) each
#define K2BLK  2048
#define UVBYTES ((size_t)NNODE * 256 * 2)   // 25.6 MB
#define WTFRAG_OFF UVBYTES                  // frag-ordered W1T, 64 KB

typedef __attribute__((ext_vector_type(8)))  __bf16 bf16x8;
typedef __attribute__((ext_vector_type(16))) float  f32x16;

static __device__ __forceinline__ unsigned int pack2bf(float a, float b) {
    unsigned int ua = __float_as_uint(a);
    unsigned int ub = __float_as_uint(b);
    ua = (ua + 0x7FFFu + ((ua >> 16) & 1u)) >> 16;
    ub = (ub + 0x7FFFu + ((ub >> 16) & 1u)) >> 16;
    return (ub << 16) | (ua & 0xFFFFu);
}

// ---------------- K0: W1 -> bf16 fragment-ordered table ----------------
// Element (colhalf,ct,ks,l5,l31,j) at short-offset FIDX*256 + l31*8 + j,
// FIDX = ((colhalf*4+ct)*8+ks)*2+l5, value = W1[colhalf*128+ks*16+l5*8+j][ct*32+l31].
// With T = FIDX*32+l31 the 16-B store lands at byte T*16 (fully coalesced).
__global__ __launch_bounds__(256, 1) void w1_frag_kernel(
    const float* __restrict__ W1, unsigned short* __restrict__ w1tf)
{
    const int T = blockIdx.x * 256 + threadIdx.x;   // 4096 threads
    const int l31  = T & 31;
    const int FIDX = T >> 5;
    const int l5 = FIDX & 1, ks = (FIDX >> 1) & 7;
    const int ct = (FIDX >> 4) & 3, colhalf = FIDX >> 6;
    const int kb = colhalf * 128 + ks * 16 + l5 * 8;
    const int n  = ct * 32 + l31;
    bf16x8 v;
#pragma unroll
    for (int j = 0; j < 8; ++j) v[j] = (__bf16)W1[(kb + j) * HID + n];
    *(bf16x8*)(w1tf + (size_t)T * 8) = v;
}

// ---------------- K1: node GEMM  uv[50000][256] bf16, no LDS ----------------
__global__ __launch_bounds__(256, 3) void node_gemm_kernel(
    const float* __restrict__ h, const unsigned short* __restrict__ w1tf,
    const float* __restrict__ b1, unsigned short* __restrict__ uvs)
{
    const int t = threadIdx.x, lane = t & 63, wv = t >> 6;
    const int l31 = lane & 31, l5 = lane >> 5;

    const int group = blockIdx.x * 2 + (wv >> 1);
    if (group >= NGRP) return;
    const int colhalf = wv & 1;                 // 0 -> u cols, 1 -> v cols

    // b1 fold: only the u-half adds b1 (per-column).
    float b1v[4];
#pragma unroll
    for (int ct = 0; ct < 4; ++ct)
        b1v[ct] = (colhalf == 0) ? b1[ct * 32 + l31] : 0.0f;

    const int node  = group * 32 + l31;
    const int nodec = node < NNODE ? node : NNODE - 1;
    const float* hp = h + (size_t)nodec * HID + l5 * 8;

    f32x16 acc[4];
#pragma unroll
    for (int ct = 0; ct < 4; ++ct)
#pragma unroll
        for (int r = 0; r < 16; ++r) acc[ct][r] = 0.0f;

    // per ks: 1 A-frag (h row slice) + 4 B-frags (coalesced 16B/lane) + 4 MFMA
#pragma unroll
    for (int ks = 0; ks < 8; ++ks) {
        float4 f0 = *(const float4*)(hp + ks * 16);
        float4 f1 = *(const float4*)(hp + ks * 16 + 4);
        bf16x8 af;
        af[0] = (__bf16)f0.x; af[1] = (__bf16)f0.y;
        af[2] = (__bf16)f0.z; af[3] = (__bf16)f0.w;
        af[4] = (__bf16)f1.x; af[5] = (__bf16)f1.y;
        af[6] = (__bf16)f1.z; af[7] = (__bf16)f1.w;
#pragma unroll
        for (int ct = 0; ct < 4; ++ct) {
            const int fidx = ((colhalf * 4 + ct) * 8 + ks) * 2 + l5;
            bf16x8 bfg = *(const bf16x8*)(w1tf + (size_t)fidx * 256 + l31 * 8);
            acc[ct] = __builtin_amdgcn_mfma_f32_32x32x16_bf16(af, bfg,
                                                              acc[ct], 0, 0, 0);
        }
    }

    // store: C row=(r&3)+8*(r>>2)+4*l5 (node), col = colhalf*128+ct*32+l31.
    // add b1 (u-half) before the pair shuffle; pack col pairs -> 4-B stores.
#pragma unroll
    for (int ct = 0; ct < 4; ++ct) {
#pragma unroll
        for (int r = 0; r < 16; ++r) {
            float mine = acc[ct][r] + b1v[ct];
            float partner = __shfl_xor(mine, 1);
            if (!(l31 & 1)) {
                const int rr = (r & 3) + 8 * (r >> 2) + 4 * l5;
                const int nd = group * 32 + rr;
                if (nd < NNODE) {
                    const int n = colhalf * 128 + ct * 32 + l31;
                    *(unsigned int*)(uvs + (size_t)nd * 256 + n) =
                        pack2bf(mine, partner);
                }
            }
        }
    }
}

// ---------------- K2: edge gather + tiny MLP tail (R8, proven) ----------------
__global__ __launch_bounds__(256, 8) void edge_score_kernel(
    const unsigned short* __restrict__ uvs,
    const float* __restrict__ W2, const float* __restrict__ b2,
    const int* __restrict__ src, const int* __restrict__ dst,
    float* __restrict__ out)
{
    const int t = threadIdx.x, lane = t & 63, wv = t >> 6;
    const int c = lane & 15;        // 16-B chunk within 128-col half
    const int g = lane >> 4;        // edge-in-quad 0..3

    bool idx64;
    {
        unsigned long long m =
            __ballot((src[2 * lane + 1] == 0) && (dst[2 * lane + 1] == 0));
        idx64 = (m == ~0ULL);
    }

    float w2f[8];
#pragma unroll
    for (int j = 0; j < 8; ++j) w2f[j] = W2[c * 8 + j];
    const float b2s = b2[0];

    const int gw = blockIdx.x * 4 + wv;
    const int NW = K2BLK * 4;
    const int NQ = NEDGE / 4;

    for (int q0 = gw; q0 < NQ; q0 += 2 * NW) {
        const int q1  = q0 + NW;
        const int q1c = q1 < NQ ? q1 : NQ - 1;
        const int e0  = q0 * 4 + g;
        const int e1  = q1c * 4 + g;

        const int ns0 = idx64 ? src[2 * e0] : src[e0];
        const int nd0 = idx64 ? dst[2 * e0] : dst[e0];
        const int ns1 = idx64 ? src[2 * e1] : src[e1];
        const int nd1 = idx64 ? dst[2 * e1] : dst[e1];

        const uint4 qu0 = *(const uint4*)(uvs + (size_t)ns0 * 256 + c * 8);
        const uint4 qv0 = *(const uint4*)(uvs + (size_t)nd0 * 256 + 128 + c * 8);
        const uint4 qu1 = *(const uint4*)(uvs + (size_t)ns1 * 256 + c * 8);
        const uint4 qv1 = *(const uint4*)(uvs + (size_t)nd1 * 256 + 128 + c * 8);

#pragma unroll
        for (int half = 0; half < 2; ++half) {
            const uint4 qu = half ? qu1 : qu0;
            const uint4 qv = half ? qv1 : qv0;
            float p = 0.0f;
#pragma unroll
            for (int j = 0; j < 4; ++j) {
                const unsigned int uw = j == 0 ? qu.x : j == 1 ? qu.y
                                      : j == 2 ? qu.z : qu.w;
                const unsigned int vw = j == 0 ? qv.x : j == 1 ? qv.y
                                      : j == 2 ? qv.z : qv.w;
                float slo = __uint_as_float(uw << 16)
                          + __uint_as_float(vw << 16);
                float shi = __uint_as_float(uw & 0xFFFF0000u)
                          + __uint_as_float(vw & 0xFFFF0000u);
                slo = slo > 0.0f ? slo : 0.0f;
                shi = shi > 0.0f ? shi : 0.0f;
                p = fmaf(slo, w2f[2 * j], p);
                p = fmaf(shi, w2f[2 * j + 1], p);
            }
            p += __shfl_xor(p, 1);
            p += __shfl_xor(p, 2);
            p += __shfl_xor(p, 4);
            p += __shfl_xor(p, 8);

            if (c == 0 && (half == 0 || q1 < NQ)) {
                const int e = half ? e1 : e0;
                out[e] = 1.0f / (1.0f + __expf(-(p + b2s)));
            }
        }
    }
}

// ---------------- fallback (proven single-kernel) ----------------
__global__ __launch_bounds__(256, 1) void edge_mlp_fallback(
    const float* __restrict__ h,  const float* __restrict__ W1,
    const float* __restrict__ b1, const float* __restrict__ W2,
    const float* __restrict__ b2, const int* __restrict__ src,
    const int* __restrict__ dst,  float* __restrict__ out)
{
    __shared__ unsigned char smem[65536];
    const int t = threadIdx.x, lane = t & 63, wv = t >> 6;
    const int l31 = lane & 31, l5 = lane >> 5;
    bool idx64;
    {
        unsigned long long m =
            __ballot((src[2 * lane + 1] == 0) && (dst[2 * lane + 1] == 0));
        idx64 = (m == ~0ULL);
    }
    for (int task = t; task < 4096; task += 256) {
        int n = task & 127, slot = task >> 7;
        const float* wp = W1 + (slot * 8) * HID + n;
        bf16x8 v;
#pragma unroll
        for (int j = 0; j < 8; ++j) v[j] = (__bf16)wp[j * HID];
        *(bf16x8*)(smem + n * 512 + ((slot * 16) ^ ((n & 31) << 4))) = v;
    }
    float b1v[4], w2v[4];
#pragma unroll
    for (int ct = 0; ct < 4; ++ct) {
        int n = ct * 32 + l31;
        b1v[ct] = b1[n]; w2v[ct] = W2[n];
    }
    const float b2s = b2[0];
    __syncthreads();
    const int swz = l31 << 4;
    const int gw = blockIdx.x * 4 + wv;
    for (int tile = gw; tile < NEDGE / 32; tile += 512 * 4) {
        const int e = tile * 32 + l31;
        const long long ns = idx64 ? (long long)src[2 * e] : (long long)src[e];
        const long long nd = idx64 ? (long long)dst[2 * e] : (long long)dst[e];
        const float* hs = h + ns * HID + l5 * 8;
        const float* hd = h + nd * HID + l5 * 8;
        f32x16 acc[4];
#pragma unroll
        for (int ct = 0; ct < 4; ++ct)
#pragma unroll
            for (int r = 0; r < 16; ++r) acc[ct][r] = 0.0f;
#pragma unroll
        for (int ks = 0; ks < 16; ++ks) {
            const float* p = (ks < 8) ? (hs + ks * 16) : (hd + (ks - 8) * 16);
            float4 f0 = *(const float4*)p;
            float4 f1 = *(const float4*)(p + 4);
            bf16x8 af;
            af[0] = (__bf16)f0.x; af[1] = (__bf16)f0.y;
            af[2] = (__bf16)f0.z; af[3] = (__bf16)f0.w;
            af[4] = (__bf16)f1.x; af[5] = (__bf16)f1.y;
            af[6] = (__bf16)f1.z; af[7] = (__bf16)f1.w;
            const int coff = ks * 32 + l5 * 16;
#pragma unroll
            for (int ct = 0; ct < 4; ++ct) {
                const int n = ct * 32 + l31;
                bf16x8 bfg = *(const bf16x8*)(smem + n * 512 + (coff ^ swz));
                acc[ct] = __builtin_amdgcn_mfma_f32_32x32x16_bf16(af, bfg,
                                                                  acc[ct], 0, 0, 0);
            }
        }
        float p[16];
#pragma unroll
        for (int r = 0; r < 16; ++r) p[r] = 0.0f;
#pragma unroll
        for (int ct = 0; ct < 4; ++ct)
#pragma unroll
            for (int r = 0; r < 16; ++r) {
                float v = acc[ct][r] + b1v[ct];
                v = v > 0.0f ? v : 0.0f;
                p[r] += v * w2v[ct];
            }
#pragma unroll
        for (int r = 0; r < 16; ++r) {
            p[r] += __shfl_xor(p[r], 1);  p[r] += __shfl_xor(p[r], 2);
            p[r] += __shfl_xor(p[r], 4);  p[r] += __shfl_xor(p[r], 8);
            p[r] += __shfl_xor(p[r], 16);
        }
        if (l31 == 0) {
#pragma unroll
            for (int g = 0; g < 4; ++g) {
                const int e0 = tile * 32 + g * 8 + l5 * 4;
                float4 o4;
                o4.x = 1.0f / (1.0f + __expf(-(p[4 * g + 0] + b2s)));
                o4.y = 1.0f / (1.0f + __expf(-(p[4 * g + 1] + b2s)));
                o4.z = 1.0f / (1.0f + __expf(-(p[4 * g + 2] + b2s)));
                o4.w = 1.0f / (1.0f + __expf(-(p[4 * g + 3] + b2s)));
                *(float4*)(out + e0) = o4;
            }
        }
    }
}

extern "C" void kernel_launch(void* const* d_in, const int* in_sizes, int n_in,
                              void* d_out, int out_size, void* d_ws, size_t ws_size,
                              hipStream_t stream) {
    const float* h  = (const float*)d_in[0];
    const float* W1 = (const float*)d_in[1];
    const float* b1 = (const float*)d_in[2];
    const float* W2 = (const float*)d_in[3];
    const float* b2 = (const float*)d_in[4];
    const int* src  = (const int*)d_in[5];
    const int* dst  = (const int*)d_in[6];
    (void)in_sizes; (void)n_in; (void)out_size;

    const size_t need = WTFRAG_OFF + 65536;
    if (ws_size >= need) {
        unsigned short* uvs  = (unsigned short*)d_ws;
        unsigned short* w1tf = (unsigned short*)((char*)d_ws + WTFRAG_OFF);
        w1_frag_kernel<<<16, 256, 0, stream>>>(W1, w1tf);
        node_gemm_kernel<<<K1BLK, 256, 0, stream>>>(h, w1tf, b1, uvs);
        edge_score_kernel<<<K2BLK, 256, 0, stream>>>(uvs, W2, b2, src, dst,
                                                     (float*)d_out);
    } else {
        edge_mlp_fallback<<<512, 256, 0, stream>>>(h, W1, b1, W2, b2, src, dst,
                                                   (float*)d_out);
    }
}

// Round 11
// 73.907 us; speedup vs baseline: 1.0315x; 1.0315x over previous
//
#include <hip/hip_runtime.h>
#include <hip/hip_bf16.h>

// score = sigmoid(relu([h[src]|h[dst]]@W1 + b1) @ W2 + b2)
// R11: K0/K1 byte-identical to R9 (best total, K1 @ (256,1) max-ILP).
//      K2: unroll-4 -> 16 uv loads in flight/wave (was 8), (256,4) cap 128.
//      Tests latency-vs-fabric-wall for the random gather.

#define HID    128
#define NNODE  50000
#define NEDGE  600000
#define NGRP   ((NNODE + 31) / 32)       // 1563 node groups of 32
#define K1BLK  ((NGRP + 1) / 2)          // 782 blocks, 2 groups (4 waves) each
#define K2BLK  2048
#define UVBYTES ((size_t)NNODE * 256 * 2)   // 25.6 MB
#define WTFRAG_OFF UVBYTES                  // frag-ordered W1T, 64 KB

typedef __attribute__((ext_vector_type(8)))  __bf16 bf16x8;
typedef __attribute__((ext_vector_type(16))) float  f32x16;

static __device__ __forceinline__ unsigned int pack2bf(float a, float b) {
    unsigned int ua = __float_as_uint(a);
    unsigned int ub = __float_as_uint(b);
    ua = (ua + 0x7FFFu + ((ua >> 16) & 1u)) >> 16;
    ub = (ub + 0x7FFFu + ((ub >> 16) & 1u)) >> 16;
    return (ub << 16) | (ua & 0xFFFFu);
}

// ---------------- K0: W1 -> bf16 fragment-ordered table ----------------
__global__ __launch_bounds__(256, 1) void w1_frag_kernel(
    const float* __restrict__ W1, unsigned short* __restrict__ w1tf)
{
    const int T = blockIdx.x * 256 + threadIdx.x;   // 4096 threads
    const int l31  = T & 31;
    const int FIDX = T >> 5;
    const int l5 = FIDX & 1, ks = (FIDX >> 1) & 7;
    const int ct = (FIDX >> 4) & 3, colhalf = FIDX >> 6;
    const int kb = colhalf * 128 + ks * 16 + l5 * 8;
    const int n  = ct * 32 + l31;
    bf16x8 v;
#pragma unroll
    for (int j = 0; j < 8; ++j) v[j] = (__bf16)W1[(kb + j) * HID + n];
    *(bf16x8*)(w1tf + (size_t)T * 8) = v;
}

// ---------------- K1: node GEMM  uv[50000][256] bf16, no LDS ----------------
__global__ __launch_bounds__(256, 1) void node_gemm_kernel(
    const float* __restrict__ h, const unsigned short* __restrict__ w1tf,
    const float* __restrict__ b1, unsigned short* __restrict__ uvs)
{
    const int t = threadIdx.x, lane = t & 63, wv = t >> 6;
    const int l31 = lane & 31, l5 = lane >> 5;

    const int group = blockIdx.x * 2 + (wv >> 1);
    if (group >= NGRP) return;
    const int colhalf = wv & 1;                 // 0 -> u cols, 1 -> v cols

    float b1v[4];
#pragma unroll
    for (int ct = 0; ct < 4; ++ct)
        b1v[ct] = (colhalf == 0) ? b1[ct * 32 + l31] : 0.0f;

    const int node  = group * 32 + l31;
    const int nodec = node < NNODE ? node : NNODE - 1;
    const float* hp = h + (size_t)nodec * HID + l5 * 8;

    f32x16 acc[4];
#pragma unroll
    for (int ct = 0; ct < 4; ++ct)
#pragma unroll
        for (int r = 0; r < 16; ++r) acc[ct][r] = 0.0f;

#pragma unroll
    for (int ks = 0; ks < 8; ++ks) {
        float4 f0 = *(const float4*)(hp + ks * 16);
        float4 f1 = *(const float4*)(hp + ks * 16 + 4);
        bf16x8 af;
        af[0] = (__bf16)f0.x; af[1] = (__bf16)f0.y;
        af[2] = (__bf16)f0.z; af[3] = (__bf16)f0.w;
        af[4] = (__bf16)f1.x; af[5] = (__bf16)f1.y;
        af[6] = (__bf16)f1.z; af[7] = (__bf16)f1.w;
#pragma unroll
        for (int ct = 0; ct < 4; ++ct) {
            const int fidx = ((colhalf * 4 + ct) * 8 + ks) * 2 + l5;
            bf16x8 bfg = *(const bf16x8*)(w1tf + (size_t)fidx * 256 + l31 * 8);
            acc[ct] = __builtin_amdgcn_mfma_f32_32x32x16_bf16(af, bfg,
                                                              acc[ct], 0, 0, 0);
        }
    }

#pragma unroll
    for (int ct = 0; ct < 4; ++ct) {
#pragma unroll
        for (int r = 0; r < 16; ++r) {
            float mine = acc[ct][r] + b1v[ct];
            float partner = __shfl_xor(mine, 1);
            if (!(l31 & 1)) {
                const int rr = (r & 3) + 8 * (r >> 2) + 4 * l5;
                const int nd = group * 32 + rr;
                if (nd < NNODE) {
                    const int n = colhalf * 128 + ct * 32 + l31;
                    *(unsigned int*)(uvs + (size_t)nd * 256 + n) =
                        pack2bf(mine, partner);
                }
            }
        }
    }
}

// ---------------- K2: edge gather + tiny MLP tail, unroll-4 ----------------
// 16 lanes/edge, 4 edges/wave/quad, 4 quads in flight -> 16 uv loads + 8 idx
// loads outstanding per wave. All unrolled arrays statically indexed.
__global__ __launch_bounds__(256, 4) void edge_score_kernel(
    const unsigned short* __restrict__ uvs,
    const float* __restrict__ W2, const float* __restrict__ b2,
    const int* __restrict__ src, const int* __restrict__ dst,
    float* __restrict__ out)
{
    const int t = threadIdx.x, lane = t & 63, wv = t >> 6;
    const int c = lane & 15;        // 16-B chunk within 128-col half
    const int g = lane >> 4;        // edge-in-quad 0..3

    bool idx64;
    {
        unsigned long long m =
            __ballot((src[2 * lane + 1] == 0) && (dst[2 * lane + 1] == 0));
        idx64 = (m == ~0ULL);
    }

    float w2f[8];
#pragma unroll
    for (int j = 0; j < 8; ++j) w2f[j] = W2[c * 8 + j];
    const float b2s = b2[0];

    const int gw = blockIdx.x * 4 + wv;
    const int NW = K2BLK * 4;                 // 8192 waves
    const int NQ = NEDGE / 4;                 // 150000 quads

    for (int q0 = gw; q0 < NQ; q0 += 4 * NW) {
        int ee[4];
#pragma unroll
        for (int k = 0; k < 4; ++k) {
            int q = q0 + k * NW;
            ee[k] = (q < NQ ? q : NQ - 1) * 4 + g;   // clamp loads, guard store
        }

        // ---- phase 1: all index loads (8 in flight) ----
        int ns[4], nd[4];
#pragma unroll
        for (int k = 0; k < 4; ++k) {
            ns[k] = idx64 ? src[2 * ee[k]] : src[ee[k]];
            nd[k] = idx64 ? dst[2 * ee[k]] : dst[ee[k]];
        }

        // ---- phase 2: all table loads (16 in flight) ----
        uint4 qu[4], qv[4];
#pragma unroll
        for (int k = 0; k < 4; ++k) {
            qu[k] = *(const uint4*)(uvs + (size_t)ns[k] * 256 + c * 8);
            qv[k] = *(const uint4*)(uvs + (size_t)nd[k] * 256 + 128 + c * 8);
        }

        // ---- phase 3: VALU + reduce + store ----
#pragma unroll
        for (int k = 0; k < 4; ++k) {
            float p = 0.0f;
#pragma unroll
            for (int j = 0; j < 4; ++j) {
                const unsigned int uw = j == 0 ? qu[k].x : j == 1 ? qu[k].y
                                      : j == 2 ? qu[k].z : qu[k].w;
                const unsigned int vw = j == 0 ? qv[k].x : j == 1 ? qv[k].y
                                      : j == 2 ? qv[k].z : qv[k].w;
                float slo = __uint_as_float(uw << 16)
                          + __uint_as_float(vw << 16);
                float shi = __uint_as_float(uw & 0xFFFF0000u)
                          + __uint_as_float(vw & 0xFFFF0000u);
                slo = slo > 0.0f ? slo : 0.0f;
                shi = shi > 0.0f ? shi : 0.0f;
                p = fmaf(slo, w2f[2 * j], p);
                p = fmaf(shi, w2f[2 * j + 1], p);
            }
            p += __shfl_xor(p, 1);
            p += __shfl_xor(p, 2);
            p += __shfl_xor(p, 4);
            p += __shfl_xor(p, 8);

            if (c == 0 && (q0 + k * NW) < NQ)
                out[ee[k]] = 1.0f / (1.0f + __expf(-(p + b2s)));
        }
    }
}

// ---------------- fallback (proven single-kernel) ----------------
__global__ __launch_bounds__(256, 1) void edge_mlp_fallback(
    const float* __restrict__ h,  const float* __restrict__ W1,
    const float* __restrict__ b1, const float* __restrict__ W2,
    const float* __restrict__ b2, const int* __restrict__ src,
    const int* __restrict__ dst,  float* __restrict__ out)
{
    __shared__ unsigned char smem[65536];
    const int t = threadIdx.x, lane = t & 63, wv = t >> 6;
    const int l31 = lane & 31, l5 = lane >> 5;
    bool idx64;
    {
        unsigned long long m =
            __ballot((src[2 * lane + 1] == 0) && (dst[2 * lane + 1] == 0));
        idx64 = (m == ~0ULL);
    }
    for (int task = t; task < 4096; task += 256) {
        int n = task & 127, slot = task >> 7;
        const float* wp = W1 + (slot * 8) * HID + n;
        bf16x8 v;
#pragma unroll
        for (int j = 0; j < 8; ++j) v[j] = (__bf16)wp[j * HID];
        *(bf16x8*)(smem + n * 512 + ((slot * 16) ^ ((n & 31) << 4))) = v;
    }
    float b1v[4], w2v[4];
#pragma unroll
    for (int ct = 0; ct < 4; ++ct) {
        int n = ct * 32 + l31;
        b1v[ct] = b1[n]; w2v[ct] = W2[n];
    }
    const float b2s = b2[0];
    __syncthreads();
    const int swz = l31 << 4;
    const int gw = blockIdx.x * 4 + wv;
    for (int tile = gw; tile < NEDGE / 32; tile += 512 * 4) {
        const int e = tile * 32 + l31;
        const long long ns = idx64 ? (long long)src[2 * e] : (long long)src[e];
        const long long nd = idx64 ? (long long)dst[2 * e] : (long long)dst[e];
        const float* hs = h + ns * HID + l5 * 8;
        const float* hd = h + nd * HID + l5 * 8;
        f32x16 acc[4];
#pragma unroll
        for (int ct = 0; ct < 4; ++ct)
#pragma unroll
            for (int r = 0; r < 16; ++r) acc[ct][r] = 0.0f;
#pragma unroll
        for (int ks = 0; ks < 16; ++ks) {
            const float* p = (ks < 8) ? (hs + ks * 16) : (hd + (ks - 8) * 16);
            float4 f0 = *(const float4*)p;
            float4 f1 = *(const float4*)(p + 4);
            bf16x8 af;
            af[0] = (__bf16)f0.x; af[1] = (__bf16)f0.y;
            af[2] = (__bf16)f0.z; af[3] = (__bf16)f0.w;
            af[4] = (__bf16)f1.x; af[5] = (__bf16)f1.y;
            af[6] = (__bf16)f1.z; af[7] = (__bf16)f1.w;
            const int coff = ks * 32 + l5 * 16;
#pragma unroll
            for (int ct = 0; ct < 4; ++ct) {
                const int n = ct * 32 + l31;
                bf16x8 bfg = *(const bf16x8*)(smem + n * 512 + (coff ^ swz));
                acc[ct] = __builtin_amdgcn_mfma_f32_32x32x16_bf16(af, bfg,
                                                                  acc[ct], 0, 0, 0);
            }
        }
        float p[16];
#pragma unroll
        for (int r = 0; r < 16; ++r) p[r] = 0.0f;
#pragma unroll
        for (int ct = 0; ct < 4; ++ct)
#pragma unroll
            for (int r = 0; r < 16; ++r) {
                float v = acc[ct][r] + b1v[ct];
                v = v > 0.0f ? v : 0.0f;
                p[r] += v * w2v[ct];
            }
#pragma unroll
        for (int r = 0; r < 16; ++r) {
            p[r] += __shfl_xor(p[r], 1);  p[r] += __shfl_xor(p[r], 2);
            p[r] += __shfl_xor(p[r], 4);  p[r] += __shfl_xor(p[r], 8);
            p[r] += __shfl_xor(p[r], 16);
        }
        if (l31 == 0) {
#pragma unroll
            for (int g = 0; g < 4; ++g) {
                const int e0 = tile * 32 + g * 8 + l5 * 4;
                float4 o4;
                o4.x = 1.0f / (1.0f + __expf(-(p[4 * g + 0] + b2s)));
                o4.y = 1.0f / (1.0f + __expf(-(p[4 * g + 1] + b2s)));
                o4.z = 1.0f / (1.0f + __expf(-(p[4 * g + 2] + b2s)));
                o4.w = 1.0f / (1.0f + __expf(-(p[4 * g + 3] + b2s)));
                *(float4*)(out + e0) = o4;
            }
        }
    }
}

extern "C" void kernel_launch(void* const* d_in, const int* in_sizes, int n_in,
                              void* d_out, int out_size, void* d_ws, size_t ws_size,
                              hipStream_t stream) {
    const float* h  = (const float*)d_in[0];
    const float* W1 = (const float*)d_in[1];
    const float* b1 = (const float*)d_in[2];
    const float* W2 = (const float*)d_in[3];
    const float* b2 = (const float*)d_in[4];
    const int* src  = (const int*)d_in[5];
    const int* dst  = (const int*)d_in[6];
    (void)in_sizes; (void)n_in; (void)out_size;

    const size_t need = WTFRAG_OFF + 65536;
    if (ws_size >= need) {
        unsigned short* uvs  = (unsigned short*)d_ws;
        unsigned short* w1tf = (unsigned short*)((char*)d_ws + WTFRAG_OFF);
        w1_frag_kernel<<<16, 256, 0, stream>>>(W1, w1tf);
        node_gemm_kernel<<<K1BLK, 256, 0, stream>>>(h, w1tf, b1, uvs);
        edge_score_kernel<<<K2BLK, 256, 0, stream>>>(uvs, W2, b2, src, dst,
                                                     (float*)d_out);
    } else {
        edge_mlp_fallback<<<512, 256, 0, stream>>>(h, W1, b1, W2, b2, src, dst,
                                                   (float*)d_out);
    }
}

// Round 12
// 72.308 us; speedup vs baseline: 1.0543x; 1.0221x over previous
//
#include <hip/hip_runtime.h>
#include <hip/hip_bf16.h>

// score = sigmoid(relu([h[src]|h[dst]]@W1 + b1) @ W2 + b2)
// R12: TWO kernels (was 3) — launch-overhead attack.
//   K1': node GEMM reading W1 DIRECTLY (no K0 frag table, no LDS, no barrier).
//        B-frag element (j,lane): W1[(kb+j)*128 + ct*32+l31] -> for fixed j the
//        32 lanes hit one 128-B line: coalesced. W1 is L2-hot after block 0.
//        uv[n] = [h@W1a + b1 | h@W1b] bf16 -> d_ws.  (256,1) = proven no-spill.
//   K2:  per-edge tail, byte-identical to R8 (measured best: 42.3-42.7 us,
//        occ 68%, VGPR 24; unroll-4 regressed -> reverted).
// Budget evidence: residual(total-K2) ~29-33 us invariant across 5 different
// K1 structures => ~10 us/launch overhead dominates; cutting K0 tests this.

#define HID    128
#define NNODE  50000
#define NEDGE  600000
#define NGRP   ((NNODE + 31) / 32)       // 1563 node groups of 32
#define K1BLK  ((NGRP + 1) / 2)          // 782 blocks, 2 groups (4 waves) each
#define K2BLK  2048
#define UVBYTES ((size_t)NNODE * 256 * 2)   // 25.6 MB

typedef __attribute__((ext_vector_type(8)))  __bf16 bf16x8;
typedef __attribute__((ext_vector_type(16))) float  f32x16;

static __device__ __forceinline__ unsigned int pack2bf(float a, float b) {
    unsigned int ua = __float_as_uint(a);
    unsigned int ub = __float_as_uint(b);
    ua = (ua + 0x7FFFu + ((ua >> 16) & 1u)) >> 16;
    ub = (ub + 0x7FFFu + ((ub >> 16) & 1u)) >> 16;
    return (ub << 16) | (ua & 0xFFFFu);
}

// ---------------- K1': node GEMM  uv[50000][256] bf16, direct W1 ----------------
__global__ __launch_bounds__(256, 1) void node_gemm_kernel(
    const float* __restrict__ h, const float* __restrict__ W1,
    const float* __restrict__ b1, unsigned short* __restrict__ uvs)
{
    const int t = threadIdx.x, lane = t & 63, wv = t >> 6;
    const int l31 = lane & 31, l5 = lane >> 5;

    const int group = blockIdx.x * 2 + (wv >> 1);
    if (group >= NGRP) return;
    const int colhalf = wv & 1;                 // 0 -> u cols, 1 -> v cols

    // b1 fold: only the u-half adds b1 (per-column).
    float b1v[4];
#pragma unroll
    for (int ct = 0; ct < 4; ++ct)
        b1v[ct] = (colhalf == 0) ? b1[ct * 32 + l31] : 0.0f;

    const int node  = group * 32 + l31;
    const int nodec = node < NNODE ? node : NNODE - 1;
    const float* hp = h + (size_t)nodec * HID + l5 * 8;

    f32x16 acc[4];
#pragma unroll
    for (int ct = 0; ct < 4; ++ct)
#pragma unroll
        for (int r = 0; r < 16; ++r) acc[ct][r] = 0.0f;

    // per ks: 1 A-frag (h row slice) + 4 B-frags (direct W1, coalesced dword
    // loads: lanes l31 span 128 B per j) + 4 MFMA.
#pragma unroll
    for (int ks = 0; ks < 8; ++ks) {
        float4 f0 = *(const float4*)(hp + ks * 16);
        float4 f1 = *(const float4*)(hp + ks * 16 + 4);
        bf16x8 af;
        af[0] = (__bf16)f0.x; af[1] = (__bf16)f0.y;
        af[2] = (__bf16)f0.z; af[3] = (__bf16)f0.w;
        af[4] = (__bf16)f1.x; af[5] = (__bf16)f1.y;
        af[6] = (__bf16)f1.z; af[7] = (__bf16)f1.w;
        const int kb = colhalf * 128 + ks * 16 + l5 * 8;   // W1 row base
#pragma unroll
        for (int ct = 0; ct < 4; ++ct) {
            const int n = ct * 32 + l31;
            const float* wp = W1 + (size_t)kb * HID + n;
            bf16x8 bfg;
#pragma unroll
            for (int j = 0; j < 8; ++j) bfg[j] = (__bf16)wp[(size_t)j * HID];
            acc[ct] = __builtin_amdgcn_mfma_f32_32x32x16_bf16(af, bfg,
                                                              acc[ct], 0, 0, 0);
        }
    }

    // store: C row=(r&3)+8*(r>>2)+4*l5 (node), col = colhalf*128+ct*32+l31.
    // add b1 (u-half) before the pair shuffle; pack col pairs -> 4-B stores.
#pragma unroll
    for (int ct = 0; ct < 4; ++ct) {
#pragma unroll
        for (int r = 0; r < 16; ++r) {
            float mine = acc[ct][r] + b1v[ct];
            float partner = __shfl_xor(mine, 1);
            if (!(l31 & 1)) {
                const int rr = (r & 3) + 8 * (r >> 2) + 4 * l5;
                const int nd = group * 32 + rr;
                if (nd < NNODE) {
                    const int n = colhalf * 128 + ct * 32 + l31;
                    *(unsigned int*)(uvs + (size_t)nd * 256 + n) =
                        pack2bf(mine, partner);
                }
            }
        }
    }
}

// ---------------- K2: edge gather + tiny MLP tail (R8, measured best) ----------
__global__ __launch_bounds__(256, 8) void edge_score_kernel(
    const unsigned short* __restrict__ uvs,
    const float* __restrict__ W2, const float* __restrict__ b2,
    const int* __restrict__ src, const int* __restrict__ dst,
    float* __restrict__ out)
{
    const int t = threadIdx.x, lane = t & 63, wv = t >> 6;
    const int c = lane & 15;        // 16-B chunk within 128-col half
    const int g = lane >> 4;        // edge-in-quad 0..3

    bool idx64;
    {
        unsigned long long m =
            __ballot((src[2 * lane + 1] == 0) && (dst[2 * lane + 1] == 0));
        idx64 = (m == ~0ULL);
    }

    float w2f[8];
#pragma unroll
    for (int j = 0; j < 8; ++j) w2f[j] = W2[c * 8 + j];
    const float b2s = b2[0];

    const int gw = blockIdx.x * 4 + wv;
    const int NW = K2BLK * 4;
    const int NQ = NEDGE / 4;

    for (int q0 = gw; q0 < NQ; q0 += 2 * NW) {
        const int q1  = q0 + NW;
        const int q1c = q1 < NQ ? q1 : NQ - 1;
        const int e0  = q0 * 4 + g;
        const int e1  = q1c * 4 + g;

        const int ns0 = idx64 ? src[2 * e0] : src[e0];
        const int nd0 = idx64 ? dst[2 * e0] : dst[e0];
        const int ns1 = idx64 ? src[2 * e1] : src[e1];
        const int nd1 = idx64 ? dst[2 * e1] : dst[e1];

        const uint4 qu0 = *(const uint4*)(uvs + (size_t)ns0 * 256 + c * 8);
        const uint4 qv0 = *(const uint4*)(uvs + (size_t)nd0 * 256 + 128 + c * 8);
        const uint4 qu1 = *(const uint4*)(uvs + (size_t)ns1 * 256 + c * 8);
        const uint4 qv1 = *(const uint4*)(uvs + (size_t)nd1 * 256 + 128 + c * 8);

#pragma unroll
        for (int half = 0; half < 2; ++half) {
            const uint4 qu = half ? qu1 : qu0;
            const uint4 qv = half ? qv1 : qv0;
            float p = 0.0f;
#pragma unroll
            for (int j = 0; j < 4; ++j) {
                const unsigned int uw = j == 0 ? qu.x : j == 1 ? qu.y
                                      : j == 2 ? qu.z : qu.w;
                const unsigned int vw = j == 0 ? qv.x : j == 1 ? qv.y
                                      : j == 2 ? qv.z : qv.w;
                float slo = __uint_as_float(uw << 16)
                          + __uint_as_float(vw << 16);
                float shi = __uint_as_float(uw & 0xFFFF0000u)
                          + __uint_as_float(vw & 0xFFFF0000u);
                slo = slo > 0.0f ? slo : 0.0f;
                shi = shi > 0.0f ? shi : 0.0f;
                p = fmaf(slo, w2f[2 * j], p);
                p = fmaf(shi, w2f[2 * j + 1], p);
            }
            p += __shfl_xor(p, 1);
            p += __shfl_xor(p, 2);
            p += __shfl_xor(p, 4);
            p += __shfl_xor(p, 8);

            if (c == 0 && (half == 0 || q1 < NQ)) {
                const int e = half ? e1 : e0;
                out[e] = 1.0f / (1.0f + __expf(-(p + b2s)));
            }
        }
    }
}

// ---------------- fallback (proven single-kernel) ----------------
__global__ __launch_bounds__(256, 1) void edge_mlp_fallback(
    const float* __restrict__ h,  const float* __restrict__ W1,
    const float* __restrict__ b1, const float* __restrict__ W2,
    const float* __restrict__ b2, const int* __restrict__ src,
    const int* __restrict__ dst,  float* __restrict__ out)
{
    __shared__ unsigned char smem[65536];
    const int t = threadIdx.x, lane = t & 63, wv = t >> 6;
    const int l31 = lane & 31, l5 = lane >> 5;
    bool idx64;
    {
        unsigned long long m =
            __ballot((src[2 * lane + 1] == 0) && (dst[2 * lane + 1] == 0));
        idx64 = (m == ~0ULL);
    }
    for (int task = t; task < 4096; task += 256) {
        int n = task & 127, slot = task >> 7;
        const float* wp = W1 + (slot * 8) * HID + n;
        bf16x8 v;
#pragma unroll
        for (int j = 0; j < 8; ++j) v[j] = (__bf16)wp[j * HID];
        *(bf16x8*)(smem + n * 512 + ((slot * 16) ^ ((n & 31) << 4))) = v;
    }
    float b1v[4], w2v[4];
#pragma unroll
    for (int ct = 0; ct < 4; ++ct) {
        int n = ct * 32 + l31;
        b1v[ct] = b1[n]; w2v[ct] = W2[n];
    }
    const float b2s = b2[0];
    __syncthreads();
    const int swz = l31 << 4;
    const int gw = blockIdx.x * 4 + wv;
    for (int tile = gw; tile < NEDGE / 32; tile += 512 * 4) {
        const int e = tile * 32 + l31;
        const long long ns = idx64 ? (long long)src[2 * e] : (long long)src[e];
        const long long nd = idx64 ? (long long)dst[2 * e] : (long long)dst[e];
        const float* hs = h + ns * HID + l5 * 8;
        const float* hd = h + nd * HID + l5 * 8;
        f32x16 acc[4];
#pragma unroll
        for (int ct = 0; ct < 4; ++ct)
#pragma unroll
            for (int r = 0; r < 16; ++r) acc[ct][r] = 0.0f;
#pragma unroll
        for (int ks = 0; ks < 16; ++ks) {
            const float* p = (ks < 8) ? (hs + ks * 16) : (hd + (ks - 8) * 16);
            float4 f0 = *(const float4*)p;
            float4 f1 = *(const float4*)(p + 4);
            bf16x8 af;
            af[0] = (__bf16)f0.x; af[1] = (__bf16)f0.y;
            af[2] = (__bf16)f0.z; af[3] = (__bf16)f0.w;
            af[4] = (__bf16)f1.x; af[5] = (__bf16)f1.y;
            af[6] = (__bf16)f1.z; af[7] = (__bf16)f1.w;
            const int coff = ks * 32 + l5 * 16;
#pragma unroll
            for (int ct = 0; ct < 4; ++ct) {
                const int n = ct * 32 + l31;
                bf16x8 bfg = *(const bf16x8*)(smem + n * 512 + (coff ^ swz));
                acc[ct] = __builtin_amdgcn_mfma_f32_32x32x16_bf16(af, bfg,
                                                                  acc[ct], 0, 0, 0);
            }
        }
        float p[16];
#pragma unroll
        for (int r = 0; r < 16; ++r) p[r] = 0.0f;
#pragma unroll
        for (int ct = 0; ct < 4; ++ct)
#pragma unroll
            for (int r = 0; r < 16; ++r) {
                float v = acc[ct][r] + b1v[ct];
                v = v > 0.0f ? v : 0.0f;
                p[r] += v * w2v[ct];
            }
#pragma unroll
        for (int r = 0; r < 16; ++r) {
            p[r] += __shfl_xor(p[r], 1);  p[r] += __shfl_xor(p[r], 2);
            p[r] += __shfl_xor(p[r], 4);  p[r] += __shfl_xor(p[r], 8);
            p[r] += __shfl_xor(p[r], 16);
        }
        if (l31 == 0) {
#pragma unroll
            for (int g = 0; g < 4; ++g) {
                const int e0 = tile * 32 + g * 8 + l5 * 4;
                float4 o4;
                o4.x = 1.0f / (1.0f + __expf(-(p[4 * g + 0] + b2s)));
                o4.y = 1.0f / (1.0f + __expf(-(p[4 * g + 1] + b2s)));
                o4.z = 1.0f / (1.0f + __expf(-(p[4 * g + 2] + b2s)));
                o4.w = 1.0f / (1.0f + __expf(-(p[4 * g + 3] + b2s)));
                *(float4*)(out + e0) = o4;
            }
        }
    }
}

extern "C" void kernel_launch(void* const* d_in, const int* in_sizes, int n_in,
                              void* d_out, int out_size, void* d_ws, size_t ws_size,
                              hipStream_t stream) {
    const float* h  = (const float*)d_in[0];
    const float* W1 = (const float*)d_in[1];
    const float* b1 = (const float*)d_in[2];
    const float* W2 = (const float*)d_in[3];
    const float* b2 = (const float*)d_in[4];
    const int* src  = (const int*)d_in[5];
    const int* dst  = (const int*)d_in[6];
    (void)in_sizes; (void)n_in; (void)out_size;

    if (ws_size >= UVBYTES) {
        unsigned short* uvs = (unsigned short*)d_ws;
        node_gemm_kernel<<<K1BLK, 256, 0, stream>>>(h, W1, b1, uvs);
        edge_score_kernel<<<K2BLK, 256, 0, stream>>>(uvs, W2, b2, src, dst,
                                                     (float*)d_out);
    } else {
        edge_mlp_fallback<<<512, 256, 0, stream>>>(h, W1, b1, W2, b2, src, dst,
                                                   (float*)d_out);
    }
}